// Round 1
// baseline (298.119 us; speedup 1.0000x reference)
//
#include <hip/hip_runtime.h>
#include <math.h>

#define BB 2
#define LL 2048
#define DD 256
#define PP 32
#define PI_F 3.14159265358979323846f

// ---------------------------------------------------------------------------
// Kernel 1: encode. 8 token-rows per block, 256 threads.
//   phases = tanh(x@key_W + key_b)*pi  -> ph[row][p] = (cos, sin) interleaved
//   values = x@val_W + val_b
// ---------------------------------------------------------------------------
__global__ __launch_bounds__(256) void encode_kernel(
    const float* __restrict__ x, const float* __restrict__ key_W,
    const float* __restrict__ key_b, const float* __restrict__ val_W,
    const float* __restrict__ val_b, float2* __restrict__ ph,
    float* __restrict__ values)
{
    __shared__ float xs[256][12];   // xs[k][r], pad 12 -> float4 reads 16B-aligned
    const int tid = threadIdx.x;
    const long row0 = (long)blockIdx.x * 8;

    #pragma unroll
    for (int i = 0; i < 8; ++i)
        xs[tid][i] = x[(row0 + i) * DD + tid];   // coalesced
    __syncthreads();

    // phases: thread (r = tid>>5, p = tid&31) computes one (row, phase)
    {
        const int r = tid >> 5, p = tid & 31;
        float a = key_b[p];
        #pragma unroll 4
        for (int k = 0; k < DD; ++k)
            a += xs[k][r] * key_W[k * PP + p];
        a = tanhf(a) * PI_F;
        float sn, cs;
        sincosf(a, &sn, &cs);
        ph[(row0 + r) * PP + p] = make_float2(cs, sn);
    }

    // values: thread owns column d = tid for all 8 rows
    float acc[8];
    const float bv = val_b[tid];
    #pragma unroll
    for (int i = 0; i < 8; ++i) acc[i] = bv;
    #pragma unroll 4
    for (int k = 0; k < DD; ++k) {
        const float w = val_W[k * DD + tid];            // coalesced, L2-resident
        const float4 a0 = *(const float4*)&xs[k][0];    // uniform broadcast
        const float4 a1 = *(const float4*)&xs[k][4];
        acc[0] += a0.x * w; acc[1] += a0.y * w;
        acc[2] += a0.z * w; acc[3] += a0.w * w;
        acc[4] += a1.x * w; acc[5] += a1.y * w;
        acc[6] += a1.z * w; acc[7] += a1.w * w;
    }
    #pragma unroll
    for (int i = 0; i < 8; ++i)
        values[(row0 + i) * DD + tid] = acc[i];
}

// ---------------------------------------------------------------------------
// Kernel 2: retrieve.
//   retrieved[b,l,d] = (1/(sqrt(valid_l)*sqrt(P))) *
//       sum_{j: 2j+1<=l} [ sum_p (ph[2j]·ph[l]) ] * values[b,2j+1,d]
// Tile: 8 l-rows per block (grid B*256), 32-wide j tiles.
// Thread map (PV): g = tid>>6 owns rows {2g,2g+1}; lane = tid&63 owns d = 4*lane..+3
// ---------------------------------------------------------------------------
__global__ __launch_bounds__(256) void retrieve_kernel(
    const float2* __restrict__ ph, const float* __restrict__ values,
    float* __restrict__ retrieved)
{
    __shared__ float2 pl[8][33];    // l-tile phasors, pad -> 2-way max (free)
    __shared__ float2 pj[32][33];   // j-tile shifted phasors
    __shared__ float  S[8][33];     // score tile

    const int tid = threadIdx.x;
    const int b   = blockIdx.x >> 8;       // L/8 = 256 tiles per batch
    const int lt  = blockIdx.x & 255;
    const int l0  = lt * 8;
    const long base = (long)b * LL;

    {   // load l-tile phasors (one float2 per thread, coalesced)
        const int r = tid >> 5, p = tid & 31;
        pl[r][p] = ph[(base + l0 + r) * PP + p];
    }

    const int g = tid >> 6;
    const int lane = tid & 63;
    const int dbase = lane * 4;

    float4 acc0 = make_float4(0.f,0.f,0.f,0.f);
    float4 acc1 = make_float4(0.f,0.f,0.f,0.f);

    const int jmax = l0 / 2 + 3;           // max valid j for this tile (l0 even)
    const int njt  = jmax / 32 + 1;        // j-tiles; loaded jg <= 1023 always

    for (int jt = 0; jt < njt; ++jt) {
        __syncthreads();                   // prev PV done before pj overwrite
        #pragma unroll
        for (int q = 0; q < 4; ++q) {      // 1024 float2 / 256 threads
            const int e = tid + q * 256;
            const int j = e >> 5, pp = e & 31;
            const long jg = (long)jt * 32 + j;
            pj[j][pp] = ph[(base + 2 * jg) * PP + pp];
        }
        __syncthreads();
        {   // scores: thread computes S[tid>>5][tid&31]
            const int l = tid >> 5, j = tid & 31;
            float s = 0.f;
            #pragma unroll 8
            for (int q = 0; q < PP; ++q) {
                const float2 a = pl[l][q];     // 2-addr/wave broadcast
                const float2 c = pj[j][q];     // 2-way max (free)
                s += a.x * c.x + a.y * c.y;
            }
            const int jg = jt * 32 + j;
            if (2 * jg + 1 > l0 + l) s = 0.f;  // causal+odd mask
            S[l][j] = s;
        }
        __syncthreads();
        #pragma unroll 8
        for (int j = 0; j < 32; ++j) {
            const long jg = (long)jt * 32 + j;
            const float4 v = *(const float4*)&values[(base + 2 * jg + 1) * DD + dbase];
            const float s0 = S[2 * g][j];      // wave-uniform broadcast
            const float s1 = S[2 * g + 1][j];
            acc0.x += v.x * s0; acc0.y += v.y * s0; acc0.z += v.z * s0; acc0.w += v.w * s0;
            acc1.x += v.x * s1; acc1.y += v.y * s1; acc1.z += v.z * s1; acc1.w += v.w * s1;
        }
    }

    const float invP = 0.17677669529663687f;   // 1/sqrt(32)
    {
        const int l = l0 + 2 * g;
        int valid = (l + 1) / 2; if (valid < 1) valid = 1;
        const float sc = invP * rsqrtf((float)valid);
        float4 o = make_float4(acc0.x*sc, acc0.y*sc, acc0.z*sc, acc0.w*sc);
        *(float4*)&retrieved[(base + l) * DD + dbase] = o;
    }
    {
        const int l = l0 + 2 * g + 1;
        int valid = (l + 1) / 2; if (valid < 1) valid = 1;
        const float sc = invP * rsqrtf((float)valid);
        float4 o = make_float4(acc1.x*sc, acc1.y*sc, acc1.z*sc, acc1.w*sc);
        *(float4*)&retrieved[(base + l) * DD + dbase] = o;
    }
}

// ---------------------------------------------------------------------------
// Kernel 3: refine. 8 rows/block fused epilogue:
//   h = gelu(LN1(retrieved) @ W1 + b1); refined = h @ W2 + b2
//   out = x + LN2(refined) @ Wo + bo
// ---------------------------------------------------------------------------
__device__ inline float red32(float v) {
    v += __shfl_xor(v, 16, 32);
    v += __shfl_xor(v, 8, 32);
    v += __shfl_xor(v, 4, 32);
    v += __shfl_xor(v, 2, 32);
    v += __shfl_xor(v, 1, 32);
    return v;
}

__global__ __launch_bounds__(256) void refine_kernel(
    const float* __restrict__ retrieved, const float* __restrict__ x,
    const float* __restrict__ ln1_g, const float* __restrict__ ln1_b,
    const float* __restrict__ W1, const float* __restrict__ b1,
    const float* __restrict__ W2, const float* __restrict__ b2,
    const float* __restrict__ ln2_g, const float* __restrict__ ln2_b,
    const float* __restrict__ Wo, const float* __restrict__ bo,
    float* __restrict__ out)
{
    __shared__ float rT[256][12];   // LN1 output transposed [k][row], reused for LN2
    __shared__ float hT[512][12];   // gelu output transposed
    __shared__ float ref[8][264];   // refined rows for LN2 reduction

    const int tid = threadIdx.x;
    const long row0 = (long)blockIdx.x * 8;
    const int r = tid >> 5, lane = tid & 31;   // 32 threads per row

    // ---- Phase A: LN1 ----
    {
        float v[8], s = 0.f, sq = 0.f;
        #pragma unroll
        for (int i = 0; i < 8; ++i) {
            v[i] = retrieved[(row0 + r) * DD + lane + 32 * i];
            s += v[i]; sq += v[i] * v[i];
        }
        s = red32(s); sq = red32(sq);
        const float m = s * (1.f / 256.f);
        const float inv = rsqrtf(sq * (1.f / 256.f) - m * m + 1e-5f);
        #pragma unroll
        for (int i = 0; i < 8; ++i) {
            const int c = lane + 32 * i;
            rT[c][r] = (v[i] - m) * inv * ln1_g[c] + ln1_b[c];
        }
    }
    __syncthreads();

    // ---- Phase B: h = gelu(rhat @ W1 + b1); thread owns m = tid, tid+256 ----
    {
        float h0[8], h1[8];
        const float bb0 = b1[tid], bb1 = b1[tid + 256];
        #pragma unroll
        for (int i = 0; i < 8; ++i) { h0[i] = bb0; h1[i] = bb1; }
        #pragma unroll 4
        for (int k = 0; k < DD; ++k) {
            const float w0 = W1[k * 512 + tid];
            const float w1 = W1[k * 512 + tid + 256];
            const float4 ra = *(const float4*)&rT[k][0];  // uniform broadcast
            const float4 rb = *(const float4*)&rT[k][4];
            h0[0] += ra.x * w0; h0[1] += ra.y * w0; h0[2] += ra.z * w0; h0[3] += ra.w * w0;
            h0[4] += rb.x * w0; h0[5] += rb.y * w0; h0[6] += rb.z * w0; h0[7] += rb.w * w0;
            h1[0] += ra.x * w1; h1[1] += ra.y * w1; h1[2] += ra.z * w1; h1[3] += ra.w * w1;
            h1[4] += rb.x * w1; h1[5] += rb.y * w1; h1[6] += rb.z * w1; h1[7] += rb.w * w1;
        }
        #pragma unroll
        for (int i = 0; i < 8; ++i) {
            const float a0 = h0[i];
            const float a1 = h1[i];
            h0[i] = 0.5f * a0 * (1.f + erff(a0 * 0.70710678118654752f));
            h1[i] = 0.5f * a1 * (1.f + erff(a1 * 0.70710678118654752f));
        }
        #pragma unroll
        for (int i = 0; i < 8; ++i) {
            hT[tid][i] = h0[i];
            hT[tid + 256][i] = h1[i];
        }
    }
    __syncthreads();

    // ---- Phase C: refined = h @ W2 + b2; thread owns d = tid ----
    float f[8];
    {
        const float bb = b2[tid];
        #pragma unroll
        for (int i = 0; i < 8; ++i) f[i] = bb;
        #pragma unroll 4
        for (int mm = 0; mm < 512; ++mm) {
            const float w = W2[mm * DD + tid];
            const float4 ha = *(const float4*)&hT[mm][0];
            const float4 hb = *(const float4*)&hT[mm][4];
            f[0] += ha.x * w; f[1] += ha.y * w; f[2] += ha.z * w; f[3] += ha.w * w;
            f[4] += hb.x * w; f[5] += hb.y * w; f[6] += hb.z * w; f[7] += hb.w * w;
        }
    }
    #pragma unroll
    for (int i = 0; i < 8; ++i) ref[i][tid] = f[i];
    __syncthreads();

    // ---- Phase D: LN2 ----
    {
        float u[8], s = 0.f, sq = 0.f;
        #pragma unroll
        for (int i = 0; i < 8; ++i) {
            u[i] = ref[r][lane + 32 * i];
            s += u[i]; sq += u[i] * u[i];
        }
        s = red32(s); sq = red32(sq);
        const float m = s * (1.f / 256.f);
        const float inv = rsqrtf(sq * (1.f / 256.f) - m * m + 1e-5f);
        #pragma unroll
        for (int i = 0; i < 8; ++i) {
            const int c = lane + 32 * i;
            rT[c][r] = (u[i] - m) * inv * ln2_g[c] + ln2_b[c];   // reuse rT (B done)
        }
    }
    __syncthreads();

    // ---- Phase E: out = x + shat @ Wo + bo ----
    {
        float o[8];
        const float bb = bo[tid];
        #pragma unroll
        for (int i = 0; i < 8; ++i) o[i] = bb;
        #pragma unroll 4
        for (int k = 0; k < DD; ++k) {
            const float w = Wo[k * DD + tid];
            const float4 sa = *(const float4*)&rT[k][0];
            const float4 sb = *(const float4*)&rT[k][4];
            o[0] += sa.x * w; o[1] += sa.y * w; o[2] += sa.z * w; o[3] += sa.w * w;
            o[4] += sb.x * w; o[5] += sb.y * w; o[6] += sb.z * w; o[7] += sb.w * w;
        }
        #pragma unroll
        for (int i = 0; i < 8; ++i)
            out[(row0 + i) * DD + tid] = x[(row0 + i) * DD + tid] + o[i];
    }
}

// ---------------------------------------------------------------------------
extern "C" void kernel_launch(void* const* d_in, const int* in_sizes, int n_in,
                              void* d_out, int out_size, void* d_ws, size_t ws_size,
                              hipStream_t stream)
{
    const float* x     = (const float*)d_in[0];
    const float* key_W = (const float*)d_in[1];
    const float* key_b = (const float*)d_in[2];
    const float* val_W = (const float*)d_in[3];
    const float* val_b = (const float*)d_in[4];
    const float* ln1_g = (const float*)d_in[5];
    const float* ln1_b = (const float*)d_in[6];
    const float* W1    = (const float*)d_in[7];
    const float* b1    = (const float*)d_in[8];
    const float* W2    = (const float*)d_in[9];
    const float* b2    = (const float*)d_in[10];
    const float* ln2_g = (const float*)d_in[11];
    const float* ln2_b = (const float*)d_in[12];
    const float* Wo    = (const float*)d_in[13];
    const float* bo    = (const float*)d_in[14];
    float* outp = (float*)d_out;

    float* ws = (float*)d_ws;
    float2* ph       = (float2*)ws;                 // B*L*P float2  (262144 floats)
    float* values    = ws + 2 * BB * LL * PP;       // B*L*D         (1048576 floats)
    float* retrieved = values + (long)BB * LL * DD; // B*L*D         (1048576 floats)

    encode_kernel<<<BB * LL / 8, 256, 0, stream>>>(x, key_W, key_b, val_W, val_b,
                                                   ph, values);
    retrieve_kernel<<<BB * (LL / 8), 256, 0, stream>>>(ph, values, retrieved);
    refine_kernel<<<BB * LL / 8, 256, 0, stream>>>(retrieved, x, ln1_g, ln1_b,
                                                   W1, b1, W2, b2, ln2_g, ln2_b,
                                                   Wo, bo, outp);
}

// Round 2
// 257.595 us; speedup vs baseline: 1.1573x; 1.1573x over previous
//
#include <hip/hip_runtime.h>
#include <math.h>

#define BB 2
#define LL 2048
#define DD 256
#define PP 32
#define PI_F 3.14159265358979323846f

// ---------------------------------------------------------------------------
// Kernel 1: encode. 8 token-rows per block, 256 threads.
// ---------------------------------------------------------------------------
__global__ __launch_bounds__(256) void encode_kernel(
    const float* __restrict__ x, const float* __restrict__ key_W,
    const float* __restrict__ key_b, const float* __restrict__ val_W,
    const float* __restrict__ val_b, float2* __restrict__ ph,
    float* __restrict__ values)
{
    __shared__ float xs[256][12];
    const int tid = threadIdx.x;
    const long row0 = (long)blockIdx.x * 8;

    #pragma unroll
    for (int i = 0; i < 8; ++i)
        xs[tid][i] = x[(row0 + i) * DD + tid];
    __syncthreads();

    {   // phases
        const int r = tid >> 5, p = tid & 31;
        float a = key_b[p];
        #pragma unroll 8
        for (int k = 0; k < DD; ++k)
            a += xs[k][r] * key_W[k * PP + p];
        a = tanhf(a) * PI_F;
        float sn, cs;
        sincosf(a, &sn, &cs);
        ph[(row0 + r) * PP + p] = make_float2(cs, sn);
    }

    // values: thread owns column d = tid
    float acc[8];
    const float bv = val_b[tid];
    #pragma unroll
    for (int i = 0; i < 8; ++i) acc[i] = bv;
    #pragma unroll 8
    for (int k = 0; k < DD; ++k) {
        const float w = val_W[k * DD + tid];
        const float4 a0 = *(const float4*)&xs[k][0];
        const float4 a1 = *(const float4*)&xs[k][4];
        acc[0] += a0.x * w; acc[1] += a0.y * w;
        acc[2] += a0.z * w; acc[3] += a0.w * w;
        acc[4] += a1.x * w; acc[5] += a1.y * w;
        acc[6] += a1.z * w; acc[7] += a1.w * w;
    }
    #pragma unroll
    for (int i = 0; i < 8; ++i)
        values[(row0 + i) * DD + tid] = acc[i];
}

// ---------------------------------------------------------------------------
// Kernel 2: retrieve. 8 l-rows/block, 32-wide j tiles.
// S stored transposed [j][row] (pad 10, 8B-aligned float2 reads).
// ---------------------------------------------------------------------------
__global__ __launch_bounds__(256) void retrieve_kernel(
    const float2* __restrict__ ph, const float* __restrict__ values,
    float* __restrict__ retrieved)
{
    __shared__ float2 pl[8][33];
    __shared__ float2 pj[32][33];
    __shared__ float  S[32][10];   // [j][l], pad 10 -> aligned float2, ~2-way writes

    const int tid = threadIdx.x;
    const int b   = blockIdx.x >> 8;
    const int lt  = blockIdx.x & 255;
    const int l0  = lt * 8;
    const long base = (long)b * LL;

    {
        const int r = tid >> 5, p = tid & 31;
        pl[r][p] = ph[(base + l0 + r) * PP + p];
    }

    const int g = tid >> 6;
    const int lane = tid & 63;
    const int dbase = lane * 4;

    float4 acc0 = make_float4(0.f,0.f,0.f,0.f);
    float4 acc1 = make_float4(0.f,0.f,0.f,0.f);

    const int jmax = l0 / 2 + 3;
    const int njt  = jmax / 32 + 1;

    for (int jt = 0; jt < njt; ++jt) {
        __syncthreads();
        #pragma unroll
        for (int q = 0; q < 4; ++q) {
            const int e = tid + q * 256;
            const int j = e >> 5, pp = e & 31;
            const long jg = (long)jt * 32 + j;
            pj[j][pp] = ph[(base + 2 * jg) * PP + pp];
        }
        __syncthreads();
        {   // scores: thread (l = tid>>5, j = tid&31) -> S[j][l]
            const int l = tid >> 5, j = tid & 31;
            float s = 0.f;
            #pragma unroll
            for (int q = 0; q < PP; ++q) {
                const float2 a = pl[l][q];
                const float2 c = pj[j][q];
                s += a.x * c.x + a.y * c.y;
            }
            const int jg = jt * 32 + j;
            if (2 * jg + 1 > l0 + l) s = 0.f;
            S[j][l] = s;
        }
        __syncthreads();
        #pragma unroll 16
        for (int j = 0; j < 32; ++j) {
            const long jg = (long)jt * 32 + j;
            const float4 v = *(const float4*)&values[(base + 2 * jg + 1) * DD + dbase];
            const float2 ss = *(const float2*)&S[j][2 * g];   // broadcast, aligned
            acc0.x += v.x * ss.x; acc0.y += v.y * ss.x; acc0.z += v.z * ss.x; acc0.w += v.w * ss.x;
            acc1.x += v.x * ss.y; acc1.y += v.y * ss.y; acc1.z += v.z * ss.y; acc1.w += v.w * ss.y;
        }
    }

    const float invP = 0.17677669529663687f;   // 1/sqrt(32)
    {
        const int l = l0 + 2 * g;
        int valid = (l + 1) / 2; if (valid < 1) valid = 1;
        const float sc = invP * rsqrtf((float)valid);
        float4 o = make_float4(acc0.x*sc, acc0.y*sc, acc0.z*sc, acc0.w*sc);
        *(float4*)&retrieved[(base + l) * DD + dbase] = o;
    }
    {
        const int l = l0 + 2 * g + 1;
        int valid = (l + 1) / 2; if (valid < 1) valid = 1;
        const float sc = invP * rsqrtf((float)valid);
        float4 o = make_float4(acc1.x*sc, acc1.y*sc, acc1.z*sc, acc1.w*sc);
        *(float4*)&retrieved[(base + l) * DD + dbase] = o;
    }
}

// ---------------------------------------------------------------------------
// Kernel 3: refine. 8 rows/block fused LN1->W1->GELU->W2->LN2->Wo+residual.
// ---------------------------------------------------------------------------
__device__ inline float red32(float v) {
    v += __shfl_xor(v, 16, 32);
    v += __shfl_xor(v, 8, 32);
    v += __shfl_xor(v, 4, 32);
    v += __shfl_xor(v, 2, 32);
    v += __shfl_xor(v, 1, 32);
    return v;
}

__global__ __launch_bounds__(256) void refine_kernel(
    const float* __restrict__ retrieved, const float* __restrict__ x,
    const float* __restrict__ ln1_g, const float* __restrict__ ln1_b,
    const float* __restrict__ W1, const float* __restrict__ b1,
    const float* __restrict__ W2, const float* __restrict__ b2,
    const float* __restrict__ ln2_g, const float* __restrict__ ln2_b,
    const float* __restrict__ Wo, const float* __restrict__ bo,
    float* __restrict__ out)
{
    __shared__ float rT[256][12];
    __shared__ float hT[512][12];
    __shared__ float ref[8][264];

    const int tid = threadIdx.x;
    const long row0 = (long)blockIdx.x * 8;
    const int r = tid >> 5, lane = tid & 31;

    // ---- Phase A: LN1 ----
    {
        float v[8], s = 0.f, sq = 0.f;
        #pragma unroll
        for (int i = 0; i < 8; ++i) {
            v[i] = retrieved[(row0 + r) * DD + lane + 32 * i];
            s += v[i]; sq += v[i] * v[i];
        }
        s = red32(s); sq = red32(sq);
        const float m = s * (1.f / 256.f);
        const float inv = rsqrtf(sq * (1.f / 256.f) - m * m + 1e-5f);
        #pragma unroll
        for (int i = 0; i < 8; ++i) {
            const int c = lane + 32 * i;
            rT[c][r] = (v[i] - m) * inv * ln1_g[c] + ln1_b[c];
        }
    }
    __syncthreads();

    // ---- Phase B: h = gelu(rhat @ W1 + b1) ----
    {
        float h0[8], h1[8];
        const float bb0 = b1[tid], bb1 = b1[tid + 256];
        #pragma unroll
        for (int i = 0; i < 8; ++i) { h0[i] = bb0; h1[i] = bb1; }
        #pragma unroll 8
        for (int k = 0; k < DD; ++k) {
            const float w0 = W1[k * 512 + tid];
            const float w1 = W1[k * 512 + tid + 256];
            const float4 ra = *(const float4*)&rT[k][0];
            const float4 rb = *(const float4*)&rT[k][4];
            h0[0] += ra.x * w0; h0[1] += ra.y * w0; h0[2] += ra.z * w0; h0[3] += ra.w * w0;
            h0[4] += rb.x * w0; h0[5] += rb.y * w0; h0[6] += rb.z * w0; h0[7] += rb.w * w0;
            h1[0] += ra.x * w1; h1[1] += ra.y * w1; h1[2] += ra.z * w1; h1[3] += ra.w * w1;
            h1[4] += rb.x * w1; h1[5] += rb.y * w1; h1[6] += rb.z * w1; h1[7] += rb.w * w1;
        }
        #pragma unroll
        for (int i = 0; i < 8; ++i) {
            const float a0 = h0[i];
            const float a1 = h1[i];
            h0[i] = 0.5f * a0 * (1.f + erff(a0 * 0.70710678118654752f));
            h1[i] = 0.5f * a1 * (1.f + erff(a1 * 0.70710678118654752f));
        }
        #pragma unroll
        for (int i = 0; i < 8; ++i) {
            hT[tid][i] = h0[i];
            hT[tid + 256][i] = h1[i];
        }
    }
    __syncthreads();

    // ---- Phase C: refined = h @ W2 + b2 ----
    float f[8];
    {
        const float bb = b2[tid];
        #pragma unroll
        for (int i = 0; i < 8; ++i) f[i] = bb;
        #pragma unroll 16
        for (int mm = 0; mm < 512; ++mm) {
            const float w = W2[mm * DD + tid];
            const float4 ha = *(const float4*)&hT[mm][0];
            const float4 hb = *(const float4*)&hT[mm][4];
            f[0] += ha.x * w; f[1] += ha.y * w; f[2] += ha.z * w; f[3] += ha.w * w;
            f[4] += hb.x * w; f[5] += hb.y * w; f[6] += hb.z * w; f[7] += hb.w * w;
        }
    }
    #pragma unroll
    for (int i = 0; i < 8; ++i) ref[i][tid] = f[i];
    __syncthreads();

    // ---- Phase D: LN2 ----
    {
        float u[8], s = 0.f, sq = 0.f;
        #pragma unroll
        for (int i = 0; i < 8; ++i) {
            u[i] = ref[r][lane + 32 * i];
            s += u[i]; sq += u[i] * u[i];
        }
        s = red32(s); sq = red32(sq);
        const float m = s * (1.f / 256.f);
        const float inv = rsqrtf(sq * (1.f / 256.f) - m * m + 1e-5f);
        #pragma unroll
        for (int i = 0; i < 8; ++i) {
            const int c = lane + 32 * i;
            rT[c][r] = (u[i] - m) * inv * ln2_g[c] + ln2_b[c];
        }
    }
    __syncthreads();

    // ---- Phase E: out = x + shat @ Wo + bo ----
    {
        float o[8];
        const float bb = bo[tid];
        #pragma unroll
        for (int i = 0; i < 8; ++i) o[i] = bb;
        #pragma unroll 8
        for (int k = 0; k < DD; ++k) {
            const float w = Wo[k * DD + tid];
            const float4 sa = *(const float4*)&rT[k][0];
            const float4 sb = *(const float4*)&rT[k][4];
            o[0] += sa.x * w; o[1] += sa.y * w; o[2] += sa.z * w; o[3] += sa.w * w;
            o[4] += sb.x * w; o[5] += sb.y * w; o[6] += sb.z * w; o[7] += sb.w * w;
        }
        #pragma unroll
        for (int i = 0; i < 8; ++i)
            out[(row0 + i) * DD + tid] = x[(row0 + i) * DD + tid] + o[i];
    }
}

// ---------------------------------------------------------------------------
extern "C" void kernel_launch(void* const* d_in, const int* in_sizes, int n_in,
                              void* d_out, int out_size, void* d_ws, size_t ws_size,
                              hipStream_t stream)
{
    const float* x     = (const float*)d_in[0];
    const float* key_W = (const float*)d_in[1];
    const float* key_b = (const float*)d_in[2];
    const float* val_W = (const float*)d_in[3];
    const float* val_b = (const float*)d_in[4];
    const float* ln1_g = (const float*)d_in[5];
    const float* ln1_b = (const float*)d_in[6];
    const float* W1    = (const float*)d_in[7];
    const float* b1    = (const float*)d_in[8];
    const float* W2    = (const float*)d_in[9];
    const float* b2    = (const float*)d_in[10];
    const float* ln2_g = (const float*)d_in[11];
    const float* ln2_b = (const float*)d_in[12];
    const float* Wo    = (const float*)d_in[13];
    const float* bo    = (const float*)d_in[14];
    float* outp = (float*)d_out;

    float* ws = (float*)d_ws;
    float2* ph       = (float2*)ws;
    float* values    = ws + 2 * BB * LL * PP;
    float* retrieved = values + (long)BB * LL * DD;

    encode_kernel<<<BB * LL / 8, 256, 0, stream>>>(x, key_W, key_b, val_W, val_b,
                                                   ph, values);
    retrieve_kernel<<<BB * (LL / 8), 256, 0, stream>>>(ph, values, retrieved);
    refine_kernel<<<BB * LL / 8, 256, 0, stream>>>(retrieved, x, ln1_g, ln1_b,
                                                   W1, b1, W2, b2, ln2_g, ln2_b,
                                                   Wo, bo, outp);
}

// Round 3
// 225.832 us; speedup vs baseline: 1.3201x; 1.1407x over previous
//
#include <hip/hip_runtime.h>
#include <math.h>

#define BB 2
#define LL 2048
#define DD 256
#define PP 32
#define NC 64            // chunks per batch (chunk = 32 rows, 16 odd positions)
#define PI_F 3.14159265358979323846f

// ---------------------------------------------------------------------------
// Kernel 1: encode. 4 token-rows per block, 256 threads, grid B*L/4 = 1024.
// ---------------------------------------------------------------------------
__global__ __launch_bounds__(256) void encode_kernel(
    const float* __restrict__ x, const float* __restrict__ key_W,
    const float* __restrict__ key_b, const float* __restrict__ val_W,
    const float* __restrict__ val_b, float2* __restrict__ ph,
    float* __restrict__ values)
{
    __shared__ float xs[256][8];
    const int tid = threadIdx.x;
    const int row0 = blockIdx.x * 4;

    #pragma unroll
    for (int i = 0; i < 4; ++i)
        xs[tid][i] = x[(row0 + i) * DD + tid];
    __syncthreads();

    if (tid < 128) {   // phases: (r = tid>>5 in 0..3, p = tid&31)
        const int r = tid >> 5, p = tid & 31;
        float a = key_b[p];
        #pragma unroll 8
        for (int k = 0; k < DD; ++k)
            a += xs[k][r] * key_W[k * PP + p];
        a = tanhf(a) * PI_F;
        float sn, cs;
        sincosf(a, &sn, &cs);
        ph[(row0 + r) * PP + p] = make_float2(cs, sn);
    }

    // values: thread owns column d = tid for 4 rows
    float acc[4];
    const float bv = val_b[tid];
    #pragma unroll
    for (int i = 0; i < 4; ++i) acc[i] = bv;
    #pragma unroll 8
    for (int k = 0; k < DD; ++k) {
        const float w = val_W[k * DD + tid];
        const float4 a0 = *(const float4*)&xs[k][0];
        acc[0] += a0.x * w; acc[1] += a0.y * w;
        acc[2] += a0.z * w; acc[3] += a0.w * w;
    }
    #pragma unroll
    for (int i = 0; i < 4; ++i)
        values[(row0 + i) * DD + tid] = acc[i];
}

// ---------------------------------------------------------------------------
// Kernel 2: bind. Per-chunk memory M_c[q][d], q in [0,64) interleaved
// (q=2p -> cos/Re, q=2p+1 -> sin/Im):
//   M_c[q][d] = sum_{j=0..15} ph[32c+2j][q] * values[32c+2j+1][d]
// Grid: B * NC * 2 (d halves) = 256 blocks, 256 threads.
// Thread: dloc = tid&31 -> d4 = dh*128 + dloc*4; qg = tid>>5 owns q = qg*8..+7
// ---------------------------------------------------------------------------
__global__ __launch_bounds__(256) void bind_kernel(
    const float2* __restrict__ ph, const float* __restrict__ values,
    float* __restrict__ M)
{
    __shared__ float phs[16][64];

    const int tid = threadIdx.x;
    const int bid = blockIdx.x;
    const int b  = bid >> 7;
    const int c  = (bid >> 1) & 63;
    const int dh = bid & 1;
    const int base = b * LL;
    const int r0 = 32 * c;

    // stage 16 shifted phasor rows (rows r0, r0+2, ..., r0+30), 64 floats each
    const float* phf = (const float*)ph;
    #pragma unroll
    for (int k = 0; k < 4; ++k) {
        const int e = tid + k * 256;
        const int j = e >> 6, q = e & 63;
        phs[j][q] = phf[(base + r0 + 2 * j) * 64 + q];
    }
    __syncthreads();

    const int d4 = dh * 128 + (tid & 31) * 4;
    const int qg = tid >> 5;
    float4 acc[8];
    #pragma unroll
    for (int qi = 0; qi < 8; ++qi) acc[qi] = make_float4(0.f,0.f,0.f,0.f);

    #pragma unroll 4
    for (int j = 0; j < 16; ++j) {
        const float4 v = *(const float4*)&values[(base + r0 + 2 * j + 1) * DD + d4];
        #pragma unroll
        for (int qi = 0; qi < 8; ++qi) {
            const float s = phs[j][qg * 8 + qi];
            acc[qi].x += v.x * s; acc[qi].y += v.y * s;
            acc[qi].z += v.z * s; acc[qi].w += v.w * s;
        }
    }

    #pragma unroll
    for (int qi = 0; qi < 8; ++qi) {
        const int q = qg * 8 + qi;
        *(float4*)&M[(((b * NC) + c) * 64 + q) * DD + d4] = acc[qi];
    }
}

// ---------------------------------------------------------------------------
// Kernel 3: prefix. In-place EXCLUSIVE prefix sum of M over chunk index c.
// Columns: (b, q, d) = 16384 per batch; each thread scans 64 chunks.
// Grid: B*16384/256 = 128 blocks.
// ---------------------------------------------------------------------------
__global__ __launch_bounds__(256) void prefix_kernel(float* __restrict__ M)
{
    const int tid = threadIdx.x;
    const int b   = blockIdx.x >> 6;
    const int col = (blockIdx.x & 63) * 256 + tid;   // [0, 16384)
    float run = 0.f;
    #pragma unroll 4
    for (int c = 0; c < NC; ++c) {
        const long a = ((long)(b * NC + c)) * 16384 + col;
        const float tmp = M[a];
        M[a] = run;
        run += tmp;
    }
}

// ---------------------------------------------------------------------------
// Kernel 4: fused retrieve2 + refine. 8 l-rows per block, grid B*L/8 = 512.
//   retrieved[l,d] = sc_l * ( sum_q phT[q][l]*Mpre[c][q][d]
//                           + sum_{j<jcnt} S[j][l]*values[32c+2j+1][d] )
// then LN1 -> W1 -> GELU -> W2 -> LN2 -> Wo + residual.
// ---------------------------------------------------------------------------
__device__ inline float red32(float v) {
    v += __shfl_xor(v, 16, 32);
    v += __shfl_xor(v, 8, 32);
    v += __shfl_xor(v, 4, 32);
    v += __shfl_xor(v, 2, 32);
    v += __shfl_xor(v, 1, 32);
    return v;
}

__global__ __launch_bounds__(256) void fused_kernel(
    const float2* __restrict__ ph, const float* __restrict__ values,
    const float* __restrict__ Mpre, const float* __restrict__ x,
    const float* __restrict__ ln1_g, const float* __restrict__ ln1_b,
    const float* __restrict__ W1, const float* __restrict__ b1,
    const float* __restrict__ W2, const float* __restrict__ b2,
    const float* __restrict__ ln2_g, const float* __restrict__ ln2_b,
    const float* __restrict__ Wo, const float* __restrict__ bo,
    float* __restrict__ out)
{
    __shared__ float phT[64][10];    // phasors of the 8 l-rows, [q][l]
    __shared__ float S[16][10];      // within-chunk scores [j][l]
    __shared__ float rT[256][12];
    __shared__ float hT[512][12];
    __shared__ float ref[8][264];    // staging for retrieved, reused in phase C

    const int tid = threadIdx.x;
    const int b   = blockIdx.x >> 8;
    const int lt  = blockIdx.x & 255;
    const int l0  = lt * 8;
    const int base = b * LL;
    const int c     = l0 >> 5;
    const int l0loc = l0 & 31;
    const int jcnt  = l0loc / 2 + 4;     // local odd positions needed (4..16)

    // ---- load phT: 8 rows x 64 q ----
    const float* phf = (const float*)ph;
    #pragma unroll
    for (int k = 0; k < 2; ++k) {
        const int e = tid + k * 256;
        const int r = e >> 6, q = e & 63;
        phT[q][r] = phf[(base + l0 + r) * 64 + q];
    }
    __syncthreads();

    // ---- scores (within-chunk triangular part) ----
    if (tid < 128) {
        const int l = tid & 7, j = tid >> 3;   // j in 0..15
        const float* ps = &phf[(base + 32 * c + 2 * j) * 64];
        float s = 0.f;
        #pragma unroll 8
        for (int q = 0; q < 64; ++q)
            s += phT[q][l] * ps[q];
        if (2 * j + 1 > l0loc + l) s = 0.f;
        S[j][l] = s;
    }

    // ---- main part: rows 2g, 2g+1 x Mpre[c] ----
    const int g = tid >> 6;
    const int d4 = (tid & 63) * 4;
    float4 acc0 = make_float4(0.f,0.f,0.f,0.f);
    float4 acc1 = make_float4(0.f,0.f,0.f,0.f);
    {
        const float* Mc = &Mpre[((long)(b * NC + c)) * 16384 + d4];
        #pragma unroll 8
        for (int q = 0; q < 64; ++q) {
            const float4 m = *(const float4*)&Mc[q * DD];
            const float2 ss = *(const float2*)&phT[q][2 * g];
            acc0.x += m.x * ss.x; acc0.y += m.y * ss.x;
            acc0.z += m.z * ss.x; acc0.w += m.w * ss.x;
            acc1.x += m.x * ss.y; acc1.y += m.y * ss.y;
            acc1.z += m.z * ss.y; acc1.w += m.w * ss.y;
        }
    }
    __syncthreads();   // S ready

    // ---- within-chunk correction ----
    for (int j = 0; j < jcnt; ++j) {
        const float4 v = *(const float4*)&values[(base + 32 * c + 2 * j + 1) * DD + d4];
        const float2 ss = *(const float2*)&S[j][2 * g];
        acc0.x += v.x * ss.x; acc0.y += v.y * ss.x;
        acc0.z += v.z * ss.x; acc0.w += v.w * ss.x;
        acc1.x += v.x * ss.y; acc1.y += v.y * ss.y;
        acc1.z += v.z * ss.y; acc1.w += v.w * ss.y;
    }

    // ---- scale + stage retrieved in LDS ----
    {
        const float invP = 0.17677669529663687f;   // 1/sqrt(32)
        const int la = l0 + 2 * g;
        int va = (la + 1) / 2; if (va < 1) va = 1;
        const float sc0 = invP * rsqrtf((float)va);
        const int lb = la + 1;
        int vb = (lb + 1) / 2; if (vb < 1) vb = 1;
        const float sc1 = invP * rsqrtf((float)vb);
        *(float4*)&ref[2 * g][d4] = make_float4(acc0.x*sc0, acc0.y*sc0, acc0.z*sc0, acc0.w*sc0);
        *(float4*)&ref[2 * g + 1][d4] = make_float4(acc1.x*sc1, acc1.y*sc1, acc1.z*sc1, acc1.w*sc1);
    }
    __syncthreads();

    const long row0 = (long)blockIdx.x * 8;
    const int r = tid >> 5, lane = tid & 31;

    // ---- Phase A: LN1 (reads ref) ----
    {
        float v[8], s = 0.f, sq = 0.f;
        #pragma unroll
        for (int i = 0; i < 8; ++i) {
            v[i] = ref[r][lane + 32 * i];
            s += v[i]; sq += v[i] * v[i];
        }
        s = red32(s); sq = red32(sq);
        const float m = s * (1.f / 256.f);
        const float inv = rsqrtf(sq * (1.f / 256.f) - m * m + 1e-5f);
        #pragma unroll
        for (int i = 0; i < 8; ++i) {
            const int cc = lane + 32 * i;
            rT[cc][r] = (v[i] - m) * inv * ln1_g[cc] + ln1_b[cc];
        }
    }
    __syncthreads();

    // ---- Phase B: h = gelu(rhat @ W1 + b1) ----
    {
        float h0[8], h1[8];
        const float bb0 = b1[tid], bb1 = b1[tid + 256];
        #pragma unroll
        for (int i = 0; i < 8; ++i) { h0[i] = bb0; h1[i] = bb1; }
        #pragma unroll 16
        for (int k = 0; k < DD; ++k) {
            const float w0 = W1[k * 512 + tid];
            const float w1 = W1[k * 512 + tid + 256];
            const float4 ra = *(const float4*)&rT[k][0];
            const float4 rb = *(const float4*)&rT[k][4];
            h0[0] += ra.x * w0; h0[1] += ra.y * w0; h0[2] += ra.z * w0; h0[3] += ra.w * w0;
            h0[4] += rb.x * w0; h0[5] += rb.y * w0; h0[6] += rb.z * w0; h0[7] += rb.w * w0;
            h1[0] += ra.x * w1; h1[1] += ra.y * w1; h1[2] += ra.z * w1; h1[3] += ra.w * w1;
            h1[4] += rb.x * w1; h1[5] += rb.y * w1; h1[6] += rb.z * w1; h1[7] += rb.w * w1;
        }
        #pragma unroll
        for (int i = 0; i < 8; ++i) {
            const float a0 = h0[i];
            const float a1 = h1[i];
            h0[i] = 0.5f * a0 * (1.f + erff(a0 * 0.70710678118654752f));
            h1[i] = 0.5f * a1 * (1.f + erff(a1 * 0.70710678118654752f));
        }
        #pragma unroll
        for (int i = 0; i < 8; ++i) {
            hT[tid][i] = h0[i];
            hT[tid + 256][i] = h1[i];
        }
    }
    __syncthreads();

    // ---- Phase C: refined = h @ W2 + b2 ----
    float f[8];
    {
        const float bb = b2[tid];
        #pragma unroll
        for (int i = 0; i < 8; ++i) f[i] = bb;
        #pragma unroll 16
        for (int mm = 0; mm < 512; ++mm) {
            const float w = W2[mm * DD + tid];
            const float4 ha = *(const float4*)&hT[mm][0];
            const float4 hb = *(const float4*)&hT[mm][4];
            f[0] += ha.x * w; f[1] += ha.y * w; f[2] += ha.z * w; f[3] += ha.w * w;
            f[4] += hb.x * w; f[5] += hb.y * w; f[6] += hb.z * w; f[7] += hb.w * w;
        }
    }
    #pragma unroll
    for (int i = 0; i < 8; ++i) ref[i][tid] = f[i];
    __syncthreads();

    // ---- Phase D: LN2 ----
    {
        float u[8], s = 0.f, sq = 0.f;
        #pragma unroll
        for (int i = 0; i < 8; ++i) {
            u[i] = ref[r][lane + 32 * i];
            s += u[i]; sq += u[i] * u[i];
        }
        s = red32(s); sq = red32(sq);
        const float m = s * (1.f / 256.f);
        const float inv = rsqrtf(sq * (1.f / 256.f) - m * m + 1e-5f);
        #pragma unroll
        for (int i = 0; i < 8; ++i) {
            const int cc = lane + 32 * i;
            rT[cc][r] = (u[i] - m) * inv * ln2_g[cc] + ln2_b[cc];
        }
    }
    __syncthreads();

    // ---- Phase E: out = x + shat @ Wo + bo ----
    {
        float o[8];
        const float bb = bo[tid];
        #pragma unroll
        for (int i = 0; i < 8; ++i) o[i] = bb;
        #pragma unroll 16
        for (int k = 0; k < DD; ++k) {
            const float w = Wo[k * DD + tid];
            const float4 sa = *(const float4*)&rT[k][0];
            const float4 sb = *(const float4*)&rT[k][4];
            o[0] += sa.x * w; o[1] += sa.y * w; o[2] += sa.z * w; o[3] += sa.w * w;
            o[4] += sb.x * w; o[5] += sb.y * w; o[6] += sb.z * w; o[7] += sb.w * w;
        }
        #pragma unroll
        for (int i = 0; i < 8; ++i)
            out[(row0 + i) * DD + tid] = x[(row0 + i) * DD + tid] + o[i];
    }
}

// ---------------------------------------------------------------------------
extern "C" void kernel_launch(void* const* d_in, const int* in_sizes, int n_in,
                              void* d_out, int out_size, void* d_ws, size_t ws_size,
                              hipStream_t stream)
{
    const float* x     = (const float*)d_in[0];
    const float* key_W = (const float*)d_in[1];
    const float* key_b = (const float*)d_in[2];
    const float* val_W = (const float*)d_in[3];
    const float* val_b = (const float*)d_in[4];
    const float* ln1_g = (const float*)d_in[5];
    const float* ln1_b = (const float*)d_in[6];
    const float* W1    = (const float*)d_in[7];
    const float* b1    = (const float*)d_in[8];
    const float* W2    = (const float*)d_in[9];
    const float* b2    = (const float*)d_in[10];
    const float* ln2_g = (const float*)d_in[11];
    const float* ln2_b = (const float*)d_in[12];
    const float* Wo    = (const float*)d_in[13];
    const float* bo    = (const float*)d_in[14];
    float* outp = (float*)d_out;

    float* ws = (float*)d_ws;
    float2* ph    = (float2*)ws;                    // B*L*P float2 = 262144 floats
    float* values = ws + 2 * BB * LL * PP;          // B*L*D = 1048576 floats
    float* M      = values + (long)BB * LL * DD;    // B*NC*64*D = 2097152 floats
    // total ws: 13.6 MB

    encode_kernel<<<BB * LL / 4, 256, 0, stream>>>(x, key_W, key_b, val_W, val_b,
                                                   ph, values);
    bind_kernel<<<BB * NC * 2, 256, 0, stream>>>(ph, values, M);
    prefix_kernel<<<BB * 64, 256, 0, stream>>>(M);
    fused_kernel<<<BB * (LL / 8), 256, 0, stream>>>(ph, values, M, x,
                                                    ln1_g, ln1_b, W1, b1, W2, b2,
                                                    ln2_g, ln2_b, Wo, bo, outp);
}